// Round 1
// baseline (59.008 us; speedup 1.0000x reference)
//
#include <hip/hip_runtime.h>
#include <hip/hip_bf16.h>

// Problem constants (from reference): B=16, N2=1024, N3=2048, D=128
#define NB   16
#define N2   1024
#define N3   2048
#define DD   128
#define OROWS (N3 + 1)   // 2049
#define OCOLS (N2 + 1)   // 1025

typedef __attribute__((ext_vector_type(8))) __bf16 bf16x8;
typedef __attribute__((ext_vector_type(4))) float  f32x4;

static __device__ __forceinline__ unsigned short f32_to_bf16(float f) {
    unsigned u = __float_as_uint(f);
    unsigned r = u + 0x7FFF + ((u >> 16) & 1);   // round-to-nearest-even
    return (unsigned short)(r >> 16);
}

// One wave per row: load 2 f32/lane, reduce sum-of-squares across 64 lanes,
// scale, write packed 2xbf16 per lane.
__global__ void normalize_kernel(const float* __restrict__ in,
                                 unsigned short* __restrict__ out, int rows) {
    int row = blockIdx.x * 4 + (threadIdx.x >> 6);
    int l   = threadIdx.x & 63;
    if (row >= rows) return;
    const float2 v = *reinterpret_cast<const float2*>(in + (size_t)row * DD + l * 2);
    float ss = v.x * v.x + v.y * v.y;
    #pragma unroll
    for (int off = 32; off; off >>= 1) ss += __shfl_xor(ss, off);
    float s = rsqrtf(ss);
    unsigned pack = (unsigned)f32_to_bf16(v.x * s) |
                    ((unsigned)f32_to_bf16(v.y * s) << 16);
    *reinterpret_cast<unsigned*>(out + (size_t)row * DD + l * 2) = pack;
}

// Zero the dustbin row (2048) and column (1024) of each batch.
__global__ void pad_zero_kernel(float* __restrict__ out) {
    int b = blockIdx.x;
    float* base = out + (size_t)b * OROWS * OCOLS;
    for (int i = threadIdx.x; i < OCOLS; i += blockDim.x)
        base[(size_t)N3 * OCOLS + i] = 0.0f;
    for (int r = threadIdx.x; r < N3; r += blockDim.x)
        base[(size_t)r * OCOLS + N2] = 0.0f;
}

// Batched GEMM: per block, one 128x128 output tile; full K=128 staged in LDS.
// A = d3n rows (M side), B = d2n rows (N side, implicitly transposed).
// LDS layout: row-major [128][128] bf16 with st-16x32 XOR swizzle
// (byte ^= (row&7)<<4) applied on the GLOBAL SOURCE for global_load_lds
// (linear dest) and on the ds_read addresses (both-sides-or-neither rule).
__global__ __launch_bounds__(256, 2)
void gemm_kernel(const unsigned short* __restrict__ d3n,
                 const unsigned short* __restrict__ d2n,
                 float* __restrict__ out) {
    __shared__ char smem[65536];  // A: [0,32768), B: [32768,65536)

    const int blk  = blockIdx.x;
    const int b    = blk >> 7;          // 128 tiles per batch (16 x 8)
    const int tile = blk & 127;
    const int ti   = tile >> 3;         // 0..15  (M tiles of 128 over N3=2048)
    const int tj   = tile & 7;          // 0..7   (N tiles of 128 over N2=1024)

    const int t = threadIdx.x;

    const char* gA = (const char*)d3n + ((size_t)(b * N3 + ti * 128) << 8); // 256 B/row
    const char* gB = (const char*)d2n + ((size_t)(b * N2 + tj * 128) << 8);

    // Stage A tile: 32 KB = 8 iters x 256 threads x 16 B
    #pragma unroll
    for (int it = 0; it < 8; ++it) {
        int o    = it * 4096 + t * 16;
        int row  = o >> 8;
        int colb = o & 255;
        int scol = colb ^ ((row & 7) << 4);
        __builtin_amdgcn_global_load_lds(
            (const __attribute__((address_space(1))) void*)(gA + row * 256 + scol),
            (__attribute__((address_space(3))) void*)(smem + o), 16, 0, 0);
    }
    // Stage B tile
    #pragma unroll
    for (int it = 0; it < 8; ++it) {
        int o    = it * 4096 + t * 16;
        int row  = o >> 8;
        int colb = o & 255;
        int scol = colb ^ ((row & 7) << 4);
        __builtin_amdgcn_global_load_lds(
            (const __attribute__((address_space(1))) void*)(gB + row * 256 + scol),
            (__attribute__((address_space(3))) void*)(smem + 32768 + o), 16, 0, 0);
    }
    __syncthreads();  // drains vmcnt before barrier (compiler-inserted)

    const int wid = t >> 6;
    const int l   = t & 63;
    const int wm  = (wid >> 1) * 64;    // wave's M offset in tile
    const int wn  = (wid & 1) * 64;     // wave's N offset in tile
    const int lr  = l & 15;             // fragment row/col
    const int kq  = l >> 4;             // k-quad 0..3
    const int sw  = (lr & 7) << 4;      // row-dependent XOR (rows are mod-16 aligned)

    f32x4 acc[4][4] = {};

    #pragma unroll
    for (int ks = 0; ks < 4; ++ks) {
        const int kb = ks * 64 + kq * 16;     // byte offset of this lane's 8 bf16
        bf16x8 af[4], bfr[4];
        #pragma unroll
        for (int mi = 0; mi < 4; ++mi) {
            int r = wm + mi * 16 + lr;
            af[mi] = *reinterpret_cast<const bf16x8*>(smem + r * 256 + (kb ^ sw));
        }
        #pragma unroll
        for (int ni = 0; ni < 4; ++ni) {
            int r = wn + ni * 16 + lr;
            bfr[ni] = *reinterpret_cast<const bf16x8*>(smem + 32768 + r * 256 + (kb ^ sw));
        }
        #pragma unroll
        for (int mi = 0; mi < 4; ++mi)
            #pragma unroll
            for (int ni = 0; ni < 4; ++ni)
                acc[mi][ni] = __builtin_amdgcn_mfma_f32_16x16x32_bf16(
                    af[mi], bfr[ni], acc[mi][ni], 0, 0, 0);
    }

    // C/D layout: col = lane&15, row = (lane>>4)*4 + reg  [measured m89/m91]
    float* obase = out + (size_t)b * OROWS * OCOLS
                       + (size_t)(ti * 128) * OCOLS + tj * 128;
    #pragma unroll
    for (int mi = 0; mi < 4; ++mi) {
        #pragma unroll
        for (int ni = 0; ni < 4; ++ni) {
            #pragma unroll
            for (int i = 0; i < 4; ++i) {
                int r = wm + mi * 16 + kq * 4 + i;
                int c = wn + ni * 16 + lr;
                obase[(size_t)r * OCOLS + c] = acc[mi][ni][i];
            }
        }
    }
}

extern "C" void kernel_launch(void* const* d_in, const int* in_sizes, int n_in,
                              void* d_out, int out_size, void* d_ws, size_t ws_size,
                              hipStream_t stream) {
    (void)in_sizes; (void)n_in; (void)out_size; (void)ws_size;
    const float* desc2d = (const float*)d_in[0];
    const float* desc3d = (const float*)d_in[2];
    // d_in[1]/d_in[3] are the (sorted, uniform) batch ids — layout is static.

    unsigned short* d2n = (unsigned short*)d_ws;                   // 16384*128 bf16 = 4 MB
    unsigned short* d3n = d2n + (size_t)NB * N2 * DD;              // 32768*128 bf16 = 8.4 MB
    float* out = (float*)d_out;

    normalize_kernel<<<(NB * N2) / 4, 256, 0, stream>>>(desc2d, d2n, NB * N2);
    normalize_kernel<<<(NB * N3) / 4, 256, 0, stream>>>(desc3d, d3n, NB * N3);
    pad_zero_kernel<<<NB, 256, 0, stream>>>(out);
    gemm_kernel<<<NB * (N3 / 128) * (N2 / 128), 256, 0, stream>>>(d3n, d2n, out);
}

// Round 2
// 42.294 us; speedup vs baseline: 1.3952x; 1.3952x over previous
//
#include <hip/hip_runtime.h>
#include <hip/hip_bf16.h>

// Problem constants (from reference): B=16, N2=1024, N3=2048, D=128
#define NB   16
#define N2   1024
#define N3   2048
#define DD   128
#define OROWS (N3 + 1)   // 2049
#define OCOLS (N2 + 1)   // 1025

typedef __attribute__((ext_vector_type(8))) __bf16 bf16x8;
typedef __attribute__((ext_vector_type(4))) float  f32x4;

static __device__ __forceinline__ unsigned short f32_to_bf16(float f) {
    unsigned u = __float_as_uint(f);
    unsigned r = u + 0x7FFF + ((u >> 16) & 1);   // round-to-nearest-even
    return (unsigned short)(r >> 16);
}

// Fused normalize for both tensors: 32 lanes per row, float4 (16B) loads,
// ushort4 (8B) bf16 stores. ws layout: [NB*N2 rows of d2n][NB*N3 rows of d3n]
// is contiguous, so dst index == global row id.
__global__ void normalize_kernel(const float* __restrict__ d2,
                                 const float* __restrict__ d3,
                                 unsigned short* __restrict__ ws) {
    const int row = blockIdx.x * 8 + (threadIdx.x >> 5);   // 8 rows per 256-thr block
    const int l   = threadIdx.x & 31;
    // 16384 % 8 == 0, so the branch is block-uniform.
    const float* src = (row < NB * N2)
        ? d2 + (size_t)row * DD
        : d3 + (size_t)(row - NB * N2) * DD;
    const float4 v = *reinterpret_cast<const float4*>(src + l * 4);
    float ss = v.x * v.x + v.y * v.y + v.z * v.z + v.w * v.w;
    #pragma unroll
    for (int off = 16; off; off >>= 1) ss += __shfl_xor(ss, off);
    const float s = rsqrtf(ss);
    ushort4 o;
    o.x = f32_to_bf16(v.x * s);
    o.y = f32_to_bf16(v.y * s);
    o.z = f32_to_bf16(v.z * s);
    o.w = f32_to_bf16(v.w * s);
    *reinterpret_cast<ushort4*>(ws + (size_t)row * DD + l * 4) = o;
}

// Batched GEMM: per block, one 128x128 output tile; full K=128 staged in LDS.
// A = d3n rows (M side), B = d2n rows (N side, implicitly transposed).
// LDS layout: row-major [128][128] bf16 with st-16x32 XOR swizzle
// (byte ^= (row&7)<<4) applied on the GLOBAL SOURCE for global_load_lds
// (linear dest) and on the ds_read addresses (both-sides-or-neither rule).
// Dustbin row/column (zeros) fused into the epilogue of edge tiles.
__global__ __launch_bounds__(256, 2)
void gemm_kernel(const unsigned short* __restrict__ d3n,
                 const unsigned short* __restrict__ d2n,
                 float* __restrict__ out) {
    __shared__ char smem[65536];  // A: [0,32768), B: [32768,65536)

    // Bijective XCD swizzle: grid = 2048 = 8 * 256. Hardware round-robins
    // dispatch index over 8 XCDs; remap so each XCD owns 256 consecutive
    // logical tiles = 2 whole batches (1.5 MB of A+B panels -> L2-resident).
    const int hw  = blockIdx.x;
    const int blk = (hw & 7) * 256 + (hw >> 3);

    const int b    = blk >> 7;          // 128 tiles per batch (16 x 8)
    const int tile = blk & 127;
    const int ti   = tile >> 3;         // 0..15  (M tiles of 128 over N3=2048)
    const int tj   = tile & 7;          // 0..7   (N tiles of 128 over N2=1024)

    const int t = threadIdx.x;

    const char* gA = (const char*)d3n + ((size_t)(b * N3 + ti * 128) << 8); // 256 B/row
    const char* gB = (const char*)d2n + ((size_t)(b * N2 + tj * 128) << 8);

    // Stage A tile: 32 KB = 8 iters x 256 threads x 16 B
    #pragma unroll
    for (int it = 0; it < 8; ++it) {
        int o    = it * 4096 + t * 16;
        int row  = o >> 8;
        int colb = o & 255;
        int scol = colb ^ ((row & 7) << 4);
        __builtin_amdgcn_global_load_lds(
            (const __attribute__((address_space(1))) void*)(gA + row * 256 + scol),
            (__attribute__((address_space(3))) void*)(smem + o), 16, 0, 0);
    }
    // Stage B tile
    #pragma unroll
    for (int it = 0; it < 8; ++it) {
        int o    = it * 4096 + t * 16;
        int row  = o >> 8;
        int colb = o & 255;
        int scol = colb ^ ((row & 7) << 4);
        __builtin_amdgcn_global_load_lds(
            (const __attribute__((address_space(1))) void*)(gB + row * 256 + scol),
            (__attribute__((address_space(3))) void*)(smem + 32768 + o), 16, 0, 0);
    }
    __syncthreads();  // compiler drains vmcnt before the barrier

    const int wid = t >> 6;
    const int l   = t & 63;
    const int wm  = (wid >> 1) * 64;    // wave's M offset in tile
    const int wn  = (wid & 1) * 64;     // wave's N offset in tile
    const int lr  = l & 15;             // fragment row/col
    const int kq  = l >> 4;             // k-quad 0..3
    const int sw  = (lr & 7) << 4;      // row-dependent XOR (rows are mod-16 aligned)

    f32x4 acc[4][4] = {};

    #pragma unroll
    for (int ks = 0; ks < 4; ++ks) {
        const int kb = ks * 64 + kq * 16;     // byte offset of this lane's 8 bf16
        bf16x8 af[4], bfr[4];
        #pragma unroll
        for (int mi = 0; mi < 4; ++mi) {
            int r = wm + mi * 16 + lr;
            af[mi] = *reinterpret_cast<const bf16x8*>(smem + r * 256 + (kb ^ sw));
        }
        #pragma unroll
        for (int ni = 0; ni < 4; ++ni) {
            int r = wn + ni * 16 + lr;
            bfr[ni] = *reinterpret_cast<const bf16x8*>(smem + 32768 + r * 256 + (kb ^ sw));
        }
        #pragma unroll
        for (int mi = 0; mi < 4; ++mi)
            #pragma unroll
            for (int ni = 0; ni < 4; ++ni)
                acc[mi][ni] = __builtin_amdgcn_mfma_f32_16x16x32_bf16(
                    af[mi], bfr[ni], acc[mi][ni], 0, 0, 0);
    }

    // C/D layout: col = lane&15, row = (lane>>4)*4 + reg  [measured m89/m91]
    // Loop order (mi, i, ni): per 16-lane group, the 4 ni-stores of one row
    // are 4 consecutive 64B segments (256B contiguous) for L2 write-combining.
    float* obase = out + (size_t)b * OROWS * OCOLS
                       + (size_t)(ti * 128) * OCOLS + tj * 128;
    #pragma unroll
    for (int mi = 0; mi < 4; ++mi) {
        #pragma unroll
        for (int i = 0; i < 4; ++i) {
            int r = wm + mi * 16 + kq * 4 + i;
            #pragma unroll
            for (int ni = 0; ni < 4; ++ni) {
                int c = wn + ni * 16 + lr;
                obase[(size_t)r * OCOLS + c] = acc[mi][ni][i];
            }
        }
    }

    // Dustbin (zero-pad) fused into edge tiles.
    float* bb = out + (size_t)b * OROWS * OCOLS;
    if (tj == 7 && t < 128)
        bb[(size_t)(ti * 128 + t) * OCOLS + N2] = 0.0f;
    if (ti == 15) {
        if (t < 128)
            bb[(size_t)N3 * OCOLS + tj * 128 + t] = 0.0f;
        if (tj == 7 && t == 128)
            bb[(size_t)N3 * OCOLS + N2] = 0.0f;
    }
}

extern "C" void kernel_launch(void* const* d_in, const int* in_sizes, int n_in,
                              void* d_out, int out_size, void* d_ws, size_t ws_size,
                              hipStream_t stream) {
    (void)in_sizes; (void)n_in; (void)out_size; (void)ws_size;
    const float* desc2d = (const float*)d_in[0];
    const float* desc3d = (const float*)d_in[2];
    // d_in[1]/d_in[3] are the (sorted, uniform) batch ids — layout is static.

    unsigned short* d2n = (unsigned short*)d_ws;                   // 16384*128 bf16 = 4 MB
    unsigned short* d3n = d2n + (size_t)NB * N2 * DD;              // 32768*128 bf16 = 8.4 MB
    float* out = (float*)d_out;

    normalize_kernel<<<(NB * (N2 + N3)) / 8, 256, 0, stream>>>(desc2d, desc3d, d2n);
    gemm_kernel<<<NB * (N3 / 128) * (N2 / 128), 256, 0, stream>>>(d3n, d2n, out);
}

// Round 3
// 40.281 us; speedup vs baseline: 1.4649x; 1.0500x over previous
//
#include <hip/hip_runtime.h>
#include <hip/hip_bf16.h>

// Problem constants (from reference): B=16, N2=1024, N3=2048, D=128
#define NB   16
#define N2   1024
#define N3   2048
#define DD   128
#define OROWS (N3 + 1)   // 2049
#define OCOLS (N2 + 1)   // 1025

typedef __attribute__((ext_vector_type(8))) __bf16 bf16x8;
typedef __attribute__((ext_vector_type(4))) float  f32x4;

static __device__ __forceinline__ unsigned short f32_to_bf16(float f) {
    unsigned u = __float_as_uint(f);
    unsigned r = u + 0x7FFF + ((u >> 16) & 1);   // round-to-nearest-even
    return (unsigned short)(r >> 16);
}

// Fused normalize for both tensors: 32 lanes per row, float4 (16B) loads,
// ushort4 (8B) bf16 stores. ws layout: [NB*N2 rows of d2n][NB*N3 rows of d3n].
__global__ void normalize_kernel(const float* __restrict__ d2,
                                 const float* __restrict__ d3,
                                 unsigned short* __restrict__ ws) {
    const int row = blockIdx.x * 8 + (threadIdx.x >> 5);
    const int l   = threadIdx.x & 31;
    const float* src = (row < NB * N2)
        ? d2 + (size_t)row * DD
        : d3 + (size_t)(row - NB * N2) * DD;
    const float4 v = *reinterpret_cast<const float4*>(src + l * 4);
    float ss = v.x * v.x + v.y * v.y + v.z * v.z + v.w * v.w;
    #pragma unroll
    for (int off = 16; off; off >>= 1) ss += __shfl_xor(ss, off);
    const float s = rsqrtf(ss);
    ushort4 o;
    o.x = f32_to_bf16(v.x * s);
    o.y = f32_to_bf16(v.y * s);
    o.z = f32_to_bf16(v.z * s);
    o.w = f32_to_bf16(v.w * s);
    *reinterpret_cast<ushort4*>(ws + (size_t)row * DD + l * 4) = o;
}

// One block = one 128(M) x 1024(N) output slab of one batch.
// Grid = 16 batches x 16 M-tiles = 256 blocks = exactly 1/CU, no tail.
// A tile (128x128 bf16, 32KB) staged once; B panel in 16 double-buffered
// 64-col chunks (2x16KB). Raw s_barrier + counted vmcnt keeps this chunk's
// stores AND next chunk's loads in flight across the barrier (never drain
// to 0 in the loop), so HBM writes stream continuously.
__global__ __launch_bounds__(512, 1)
void gemm_kernel(const unsigned short* __restrict__ d3n,
                 const unsigned short* __restrict__ d2n,
                 float* __restrict__ out) {
    __shared__ __align__(16) char smem[65536]; // A:[0,32K) B0:[32K,48K) B1:[48K,64K)

    // Bijective XCD swizzle: 256 blocks = 8 XCDs x 32; each XCD owns 2 whole
    // batches -> B panels (512KB bf16) L2-resident per XCD.
    const int hw  = blockIdx.x;
    const int blk = (hw & 7) * 32 + (hw >> 3);
    const int b   = blk >> 4;           // batch
    const int ti  = blk & 15;           // M tile (128 rows of N3=2048)

    const int t = threadIdx.x;

    const char* gA = (const char*)d3n + ((size_t)(b * N3 + ti * 128) << 8); // 256 B/row
    const char* gB = (const char*)d2n + ((size_t)(b * N2) << 8);

    // Stage A tile: 32 KB = 4 iters x 512 thr x 16 B (st-16x32 swizzle via source)
    #pragma unroll
    for (int it = 0; it < 4; ++it) {
        int o    = it * 8192 + t * 16;
        int row  = o >> 8;
        int scol = (o & 255) ^ ((row & 7) << 4);
        __builtin_amdgcn_global_load_lds(
            (const __attribute__((address_space(1))) void*)(gA + row * 256 + scol),
            (__attribute__((address_space(3))) void*)(smem + o), 16, 0, 0);
    }
    // Stage B chunk 0 into buf0: 16 KB = 2 iters x 512 thr x 16 B
    #pragma unroll
    for (int it = 0; it < 2; ++it) {
        int o    = it * 8192 + t * 16;
        int row  = o >> 8;
        int scol = (o & 255) ^ ((row & 7) << 4);
        __builtin_amdgcn_global_load_lds(
            (const __attribute__((address_space(1))) void*)(gB + row * 256 + scol),
            (__attribute__((address_space(3))) void*)(smem + 32768 + o), 16, 0, 0);
    }
    asm volatile("s_waitcnt vmcnt(0)" ::: "memory");
    __builtin_amdgcn_s_barrier();
    __builtin_amdgcn_sched_barrier(0);

    const int wid = t >> 6;             // 8 waves
    const int l   = t & 63;
    const int wm  = (wid >> 2) * 64;    // 0 / 64  : wave's M offset
    const int wn  = (wid & 3) * 16;     // 0..48   : wave's N offset within 64-col chunk
    const int lr  = l & 15;
    const int kq  = l >> 4;
    const int sw  = (lr & 7) << 4;

    // Hoist all A fragments into registers once (A LDS never changes).
    bf16x8 af[4][4];   // [ks][mi]
    #pragma unroll
    for (int ks = 0; ks < 4; ++ks) {
        const int kb = ks * 64 + kq * 16;
        #pragma unroll
        for (int mi = 0; mi < 4; ++mi) {
            int r = wm + mi * 16 + lr;
            af[ks][mi] = *reinterpret_cast<const bf16x8*>(smem + r * 256 + (kb ^ sw));
        }
    }

    float* obase = out + (size_t)b * OROWS * OCOLS + (size_t)(ti * 128) * OCOLS;

    for (int nj = 0; nj < 16; ++nj) {
        const char* bbuf = smem + 32768 + (nj & 1) * 16384;

        // Compute this 128x64 chunk.
        f32x4 acc[4] = {};   // [mi], ni==1 fragment wide (wave covers 16 cols)
        #pragma unroll
        for (int ks = 0; ks < 4; ++ks) {
            const int kb = ks * 64 + kq * 16;
            int r = wn + lr;   // B row within chunk = output col within wave strip
            bf16x8 bfr = *reinterpret_cast<const bf16x8*>(bbuf + r * 256 + (kb ^ sw));
            #pragma unroll
            for (int mi = 0; mi < 4; ++mi)
                acc[mi] = __builtin_amdgcn_mfma_f32_16x16x32_bf16(
                    af[ks][mi], bfr, acc[mi], 0, 0, 0);
        }

        // Prefetch next B chunk FIRST (so FIFO vmcnt retires these 2 loads
        // while the 16 stores below stay in flight).
        if (nj < 15) {
            const char* gBn = gB + (size_t)(nj + 1) * 16384;
            char* nbuf = smem + 32768 + ((nj + 1) & 1) * 16384;
            #pragma unroll
            for (int it = 0; it < 2; ++it) {
                int o    = it * 8192 + t * 16;
                int row  = o >> 8;
                int scol = (o & 255) ^ ((row & 7) << 4);
                __builtin_amdgcn_global_load_lds(
                    (const __attribute__((address_space(1))) void*)(gBn + row * 256 + scol),
                    (__attribute__((address_space(3))) void*)(smem + ((nbuf - smem) + o)), 16, 0, 0);
            }
        }

        // Stores: C/D layout col=lane&15, row=(lane>>4)*4+reg. 16 dword
        // stores/lane; interior 128B lines of each output row are written
        // whole by THIS block (slab spans the full 1024 cols).
        #pragma unroll
        for (int mi = 0; mi < 4; ++mi) {
            #pragma unroll
            for (int i = 0; i < 4; ++i) {
                int r = wm + mi * 16 + kq * 4 + i;
                int c = nj * 64 + wn + lr;
                obase[(size_t)r * OCOLS + c] = acc[mi][i];
            }
        }

        // Counted wait: <=16 outstanding leaves this chunk's stores in
        // flight but guarantees the 2 prefetch loads (older) retired.
        asm volatile("s_waitcnt vmcnt(16)" ::: "memory");
        __builtin_amdgcn_s_barrier();
        __builtin_amdgcn_sched_barrier(0);
    }

    // Dustbin: col 1024 for this slab's rows; row 2048 for ti==15 blocks.
    if (t < 128)
        obase[(size_t)t * OCOLS + N2] = 0.0f;
    if (ti == 15) {
        float* last = out + (size_t)b * OROWS * OCOLS + (size_t)N3 * OCOLS;
        for (int c = t; c < OCOLS; c += 512) last[c] = 0.0f;
    }
}

extern "C" void kernel_launch(void* const* d_in, const int* in_sizes, int n_in,
                              void* d_out, int out_size, void* d_ws, size_t ws_size,
                              hipStream_t stream) {
    (void)in_sizes; (void)n_in; (void)out_size; (void)ws_size;
    const float* desc2d = (const float*)d_in[0];
    const float* desc3d = (const float*)d_in[2];

    unsigned short* d2n = (unsigned short*)d_ws;                   // 16384*128 bf16
    unsigned short* d3n = d2n + (size_t)NB * N2 * DD;              // 32768*128 bf16
    float* out = (float*)d_out;

    normalize_kernel<<<(NB * (N2 + N3)) / 8, 256, 0, stream>>>(desc2d, desc3d, d2n);
    gemm_kernel<<<NB * (N3 / 128), 512, 0, stream>>>(d3n, d2n, out);
}